// Round 8
// baseline (175.270 us; speedup 1.0000x reference)
//
#include <hip/hip_runtime.h>
#include <math.h>

// Problem constants (GroupedKANLayer): B=2, C=31, D=7, H=W=192
#define NBATCH 2
#define NC 31
#define ND 7
#define NH 192
#define NW 192
#define HW (NH * NW)            // 36864
#define NP (NBATCH * HW)        // 73728 pixels
#define NBASIS 8
#define CLEN 56                 // ND * NBASIS
#define KP 70                   // CLEN + ND + ND
#define OCB 5                   // 70 = 14 * 5 -> 45 weight SGPRs/ic

// conv v7 tiling: 32-col x 16-row tile; wave owns 4 rows; thread owns
// 1 row x 2 adjacent cols. Halo per wave: 6 rows x 38-word stride.
// h index -> global col tx0-2+h (even-aligned b64 pairs everywhere).
#define CTSX 32
#define CTSY 16
#define WROWS 4
#define HR 6                    // halo rows per wave
#define HSTR 38                 // halo row stride (words)
#define NPAIRS 108              // 6 rows * 18 b64 pairs

// kan tiling: 64 pixels per block, channel-pair ILP
#define KPPB 64

// ---------------------------------------------------------------------------
// Kernel 1: ctx = mean_d x, float4-vectorized (16 B/lane).
// ---------------------------------------------------------------------------
__global__ __launch_bounds__(256) void ctx_mean_kernel(
    const float4* __restrict__ x4, float4* __restrict__ ctx4)
{
    const int HW4 = HW / 4;
    int idx = blockIdx.x * 256 + threadIdx.x;      // over NBATCH*NC*HW4
    if (idx >= NBATCH * NC * HW4) return;
    int hw4 = idx % HW4;
    int bc  = idx / HW4;
    const float4* src = x4 + (size_t)bc * (ND * HW4) + hw4;
    float4 a = src[0];
#pragma unroll
    for (int d = 1; d < ND; ++d) {
        float4 v = src[d * HW4];
        a.x += v.x; a.y += v.y; a.z += v.z; a.w += v.w;
    }
    const float inv = 1.0f / 7.0f;
    a.x *= inv; a.y *= inv; a.z *= inv; a.w *= inv;
    ctx4[idx] = a;
}

// ---------------------------------------------------------------------------
// Kernel 2 (v7): 32x16 tile, 5 oc per block (blockIdx.z uniform -> s_loads).
// Wave-private 6x38 halo strips, zero barriers, register-pipelined staging.
// All LDS traffic is b64: 9 ds_read_b64 + 2 ds_write_b64 per ic per thread
// (was 12 b32 reads + 4 b32 writes) for the same 90 FMA.
// grid = (6, 24, 14) = 2016 blocks.
// ---------------------------------------------------------------------------
__global__ __launch_bounds__(256, 4) void conv_kernel(
    const float* __restrict__ ctx, const float* __restrict__ gw,
    const float* __restrict__ gb, float* __restrict__ wts)
{
    __shared__ float tile[4][HR * HSTR];   // 4*228*4 = 3648 B

    const int tid  = threadIdx.x;
    const int lane = tid & 63;
    const int wv   = tid >> 6;
    const int tx0  = blockIdx.x * CTSX;
    const int by   = blockIdx.y;
    const int b    = by / (NH / CTSY);
    const int ty0  = (by - b * (NH / CTSY)) * CTSY;
    const int oc0  = blockIdx.z * OCB;            // uniform -> weights s_load
    const int wrow0 = wv * WROWS;

    // staging geometry: pair q = lane + 64*s; row = q/18, k = q%18
    // global cols (gc0, gc0+1) = tx0-2+2k, tx0-1+2k -> LDS h = 2k, 2k+1
    int   voff[2];
    float m0[2], m1[2];
    int   lw[2];
    bool  sv[2];
#pragma unroll
    for (int s = 0; s < 2; ++s) {
        int q = lane + 64 * s;
        sv[s] = (q < NPAIRS);
        int r = q / 18;
        int k = q - r * 18;
        int gr  = ty0 + wrow0 - 1 + r;
        int gc0 = tx0 - 2 + 2 * k;
        bool rok = (gr >= 0) && (gr < NH);
        m0[s] = (rok && gc0 >= 0 && gc0 < NW) ? 1.f : 0.f;
        m1[s] = (rok && gc0 + 1 >= 0 && gc0 + 1 < NW) ? 1.f : 0.f;
        int grc = min(max(gr, 0), NH - 1);
        int gcc = min(max(gc0, 0), NW - 2);   // stays even -> 8B aligned
        voff[s] = grc * NW + gcc;
        lw[s] = r * HSTR + 2 * k;
    }

    const float* cb  = ctx + (b * NC) * HW;
    float*       myt = tile[wv];

    {   // prologue: stage ic = 0
        float2 t[2];
#pragma unroll
        for (int s = 0; s < 2; ++s)
            t[s] = *(const float2*)(cb + voff[s]);
#pragma unroll
        for (int s = 0; s < 2; ++s) {
            t[s].x *= m0[s]; t[s].y *= m1[s];
            if (sv[s]) *(float2*)&myt[lw[s]] = t[s];
        }
    }

    float acc[OCB][2];
#pragma unroll
    for (int oc = 0; oc < OCB; ++oc) {
        float bv = gb[oc0 + oc];
        acc[oc][0] = bv; acc[oc][1] = bv;
    }

    const int cp = lane & 15;            // col pair -> cols 2cp, 2cp+1
    const int rr = lane >> 4;            // row within wave strip (0..3)
    const float* t0 = myt + rr * HSTR + 2 * cp;

    for (int ic = 0; ic < NC; ++ic) {
        // issue global loads for ic+1 early
        float2 nxt[2];
        if (ic + 1 < NC) {
            const float* src = cb + (ic + 1) * HW;
#pragma unroll
            for (int s = 0; s < 2; ++s)
                nxt[s] = *(const float2*)(src + voff[s]);
        }

        // stencil: 3 rows x 3 b64 reads; v[r] = taps {c0-1, c0, c0+1, c1+1}
        float v[3][4];
#pragma unroll
        for (int r = 0; r < 3; ++r) {
            const float* p = t0 + r * HSTR;
            float2 a = *(const float2*)(p);
            float2 bb = *(const float2*)(p + 2);
            float2 c = *(const float2*)(p + 4);
            v[r][0] = a.y; v[r][1] = bb.x; v[r][2] = bb.y; v[r][3] = c.x;
        }

        const float* wb = gw + (oc0 * NC + ic) * 9;
#pragma unroll
        for (int oc = 0; oc < OCB; ++oc) {
            const float* w9 = wb + oc * (NC * 9);
#pragma unroll
            for (int r = 0; r < 3; ++r) {
                float wa = w9[r * 3], wbv = w9[r * 3 + 1], wc = w9[r * 3 + 2];
                acc[oc][0] += v[r][0] * wa + v[r][1] * wbv + v[r][2] * wc;
                acc[oc][1] += v[r][1] * wa + v[r][2] * wbv + v[r][3] * wc;
            }
        }

        // write ic+1 (vmcnt waits land here, behind the FMA block)
        if (ic + 1 < NC) {
#pragma unroll
            for (int s = 0; s < 2; ++s) {
                nxt[s].x *= m0[s]; nxt[s].y *= m1[s];
                if (sv[s]) *(float2*)&myt[lw[s]] = nxt[s];
            }
        }
    }

    const int p = b * HW + (ty0 + wrow0 + rr) * NW + (tx0 + 2 * cp);
#pragma unroll
    for (int oc = 0; oc < OCB; ++oc) {
        float2 o; o.x = acc[oc][0]; o.y = acc[oc][1];
        *(float2*)(wts + (size_t)(oc0 + oc) * NP + p) = o;
    }
}

// ---------------------------------------------------------------------------
// kan helpers
// ---------------------------------------------------------------------------
__device__ __forceinline__ float spline_part(float xv, const float* cb, int d)
{
    // cardinal cubic B-spline on uniform knots; cb = scoef + lane,
    // coef gather at LDS stride 64 words (bank = lane%32, 2-way = free)
    float t = (xv + 2.2f) * 2.5f;
    float fi = floorf(t);
    int i = (int)fi;
    float u = t - fi;
    float u2 = u * u, u3 = u2 * u;
    float um = 1.f - u;
    float w0 = um * um * um * (1.f / 6.f);
    float w3 = u3 * (1.f / 6.f);
    float w1 = (3.f * u3 - 6.f * u2 + 4.f) * (1.f / 6.f);
    float w2 = 1.f - w0 - w1 - w3;          // partition of unity
    int j0 = i - 3;
    float sd = 0.f;
#pragma unroll
    for (int k = 0; k < 4; ++k) {
        int j = j0 + k;
        bool valid = (j >= 0) && (j <= 7);
        int jc = valid ? j : 0;
        float wk = (k == 0) ? w0 : (k == 1) ? w1 : (k == 2) ? w2 : w3;
        float cf = cb[(d * NBASIS + jc) * KPPB];
        sd += (valid ? wk : 0.f) * cf;
    }
    return sd;
}

__device__ __forceinline__ float silu(float xv)
{
    return xv / (1.f + __expf(-xv));
}

// ---------------------------------------------------------------------------
// Kernel 3 (v8): block = 64 pixels, 4 waves. All 70 wts rows staged to LDS
// [k][64] via float4 (1120 b128 writes vs 4480 b32). Wave wv processes 8
// channels as 4 pairs (two independent spline chains per d). Wave 3 covers
// channels 23..30 (ch 23 duplicated by waves 2&3 -> identical value, benign).
// grid = 1152 blocks.
// ---------------------------------------------------------------------------
__global__ __launch_bounds__(256, 3) void kan_kernel(
    const float* __restrict__ x, const float* __restrict__ wts,
    float* __restrict__ out)
{
    __shared__ float scoef[KP * KPPB];   // 70*64*4 = 17920 B
    const int tid = threadIdx.x;
    const int p0  = blockIdx.x * KPPB;

    // stage: 70 rows x 16 float4 = 1120 vector copies, fully coalesced
    for (int f = tid; f < KP * (KPPB / 4); f += 256) {
        int k = f >> 4;
        int q = f & 15;
        float4 t = *(const float4*)(wts + (size_t)k * NP + p0 + q * 4);
        *(float4*)&scoef[k * KPPB + q * 4] = t;
    }

    __syncthreads();

    const int lane = tid & 63;
    const int wv   = tid >> 6;
    const int p    = p0 + lane;
    const int b    = p / HW;              // uniform (HW % 64 == 0)
    const int hw   = p - b * HW;

    const float* cb64 = scoef + lane;

    float uw[ND], rw[ND];
#pragma unroll
    for (int d = 0; d < ND; ++d) uw[d] = cb64[(CLEN + d) * KPPB];
#pragma unroll
    for (int d = 0; d < ND; ++d) rw[d] = cb64[(CLEN + ND + d) * KPPB];

    const float* xb = x + (size_t)(b * NC) * (ND * HW) + hw;
    float* ob = out + (b * NC) * HW + hw;

    const int c_begin = (wv == 3) ? 23 : wv * 8;   // 8 channels per wave

#pragma unroll
    for (int i = 0; i < 4; ++i) {
        const int c0 = c_begin + 2 * i;
        const int c1 = c0 + 1;
        const float* x0 = xb + (size_t)c0 * ND * HW;
        const float* x1 = xb + (size_t)c1 * ND * HW;
        float s0 = 0.f, s1 = 0.f;
#pragma unroll
        for (int d = 0; d < ND; ++d) {
            float xv0 = x0[d * HW];
            float xv1 = x1[d * HW];
            s0 += uw[d] * spline_part(xv0, cb64, d) + rw[d] * silu(xv0);
            s1 += uw[d] * spline_part(xv1, cb64, d) + rw[d] * silu(xv1);
        }
        ob[c0 * HW] = s0;
        ob[c1 * HW] = s1;
    }
}

// ---------------------------------------------------------------------------
extern "C" void kernel_launch(void* const* d_in, const int* in_sizes, int n_in,
                              void* d_out, int out_size, void* d_ws, size_t ws_size,
                              hipStream_t stream)
{
    const float* x  = (const float*)d_in[0];   // (2,31,7,192,192)
    const float* gw = (const float*)d_in[1];   // (70,31,3,3)
    const float* gb = (const float*)d_in[2];   // (70,)
    float* out = (float*)d_out;                // (2,31,192,192)

    float* ctx = (float*)d_ws;                       // 9.1 MB
    float* wts = ctx + (size_t)NBATCH * NC * HW;     // 20.6 MB

    int n4 = NBATCH * NC * (HW / 4);
    ctx_mean_kernel<<<dim3((n4 + 255) / 256), 256, 0, stream>>>(
        (const float4*)x, (float4*)ctx);
    conv_kernel<<<dim3(NW / CTSX, (NH / CTSY) * NBATCH, KP / OCB), 256, 0, stream>>>(ctx, gw, gb, wts);
    kan_kernel<<<dim3(NP / KPPB), 256, 0, stream>>>(x, wts, out);
}

// Round 9
// 171.556 us; speedup vs baseline: 1.0216x; 1.0216x over previous
//
#include <hip/hip_runtime.h>
#include <math.h>

// Problem constants (GroupedKANLayer): B=2, C=31, D=7, H=W=192
#define NBATCH 2
#define NC 31
#define ND 7
#define NH 192
#define NW 192
#define HW (NH * NW)            // 36864
#define NP (NBATCH * HW)        // 73728 pixels
#define NBASIS 8
#define CLEN 56                 // ND * NBASIS
#define KP 70                   // CLEN + ND + ND
#define OCB 5                   // 70 = 14 * 5 -> 45 weight SGPRs/ic

// conv v8 tiling: 32x32 tile; wave owns 8 rows; thread owns 1 row x 4 cols.
// Halo per wave: 10 rows x 35-word stride (odd -> all b32 accesses 2/bank).
#define CTS 32
#define WROWS 8                 // tile rows per wave
#define HROWS 10                // halo rows per wave (8 + 2)
#define HSTR 35                 // halo row stride in words (34 used + 1 pad)
#define WCELLS (HROWS * HSTR)   // 350 words per wave
#define NSLOT 6                 // ceil(350/64) staging slots per lane

// kan tiling: 64 pixels per block, channel-pair ILP
#define KPPB 64

// ---------------------------------------------------------------------------
// Kernel 1: ctx = mean_d x, float4-vectorized (16 B/lane).
// ---------------------------------------------------------------------------
__global__ __launch_bounds__(256) void ctx_mean_kernel(
    const float4* __restrict__ x4, float4* __restrict__ ctx4)
{
    const int HW4 = HW / 4;
    int idx = blockIdx.x * 256 + threadIdx.x;      // over NBATCH*NC*HW4
    if (idx >= NBATCH * NC * HW4) return;
    int hw4 = idx % HW4;
    int bc  = idx / HW4;
    const float4* src = x4 + (size_t)bc * (ND * HW4) + hw4;
    float4 a = src[0];
#pragma unroll
    for (int d = 1; d < ND; ++d) {
        float4 v = src[d * HW4];
        a.x += v.x; a.y += v.y; a.z += v.z; a.w += v.w;
    }
    const float inv = 1.0f / 7.0f;
    a.x *= inv; a.y *= inv; a.z *= inv; a.w *= inv;
    ctx4[idx] = a;
}

// ---------------------------------------------------------------------------
// Kernel 2 (v8): 32x32 tile, 5 oc per block (blockIdx.z uniform -> s_loads).
// Wave-private 10x35 halo strips, zero barriers, register-pipelined staging.
// Thread = (row, 4 cols): per ic 18 b32 reads + ~5.5 b32 writes serve 4 px
// (0.53 LDS-cyc/px vs 0.73 in the 2-px layout). All b32, odd stride ->
// exactly 2 lanes/bank everywhere. Output = float4 stores.
// grid = (6, 12, 14) = 1008 blocks -> 4 blocks/CU.
// ---------------------------------------------------------------------------
__global__ __launch_bounds__(256, 4) void conv_kernel(
    const float* __restrict__ ctx, const float* __restrict__ gw,
    const float* __restrict__ gb, float* __restrict__ wts)
{
    __shared__ float tile[4][WCELLS];   // 4*350*4 = 5600 B

    const int tid  = threadIdx.x;
    const int lane = tid & 63;
    const int wv   = tid >> 6;
    const int tx0  = blockIdx.x * CTS;
    const int by   = blockIdx.y;
    const int b    = by / (NH / CTS);
    const int ty0  = (by - b * (NH / CTS)) * CTS;
    const int oc0  = blockIdx.z * OCB;            // uniform -> weights s_load
    const int wrow0 = wv * WROWS;

    // staging geometry: cell = lane + 64*s; halo word h at row r holds
    // global (ty0+wrow0-1+r, tx0-1+h), h in [0,34)
    int   off[NSLOT];
    float msk[NSLOT];
    bool  stv[NSLOT];
#pragma unroll
    for (int s = 0; s < NSLOT; ++s) {
        int cell = lane + s * 64;
        int r = cell / HSTR;
        int h = cell - r * HSTR;
        int gh = ty0 + wrow0 + r - 1;
        int gc = tx0 + h - 1;
        bool ok = (gh >= 0) && (gh < NH) && (gc >= 0) && (gc < NW) && (h < 34);
        int ghc = min(max(gh, 0), NH - 1);
        int gcc = min(max(gc, 0), NW - 1);
        off[s] = ghc * NW + gcc;
        msk[s] = ok ? 1.f : 0.f;
        stv[s] = (cell < WCELLS);
    }

    const float* cb  = ctx + (b * NC) * HW;
    float*       myt = tile[wv];

    {   // prologue: stage ic = 0
        float t[NSLOT];
#pragma unroll
        for (int s = 0; s < NSLOT; ++s) t[s] = cb[off[s]] * msk[s];
#pragma unroll
        for (int s = 0; s < NSLOT; ++s)
            if (stv[s]) myt[lane + s * 64] = t[s];
    }

    float acc[OCB][4];
#pragma unroll
    for (int oc = 0; oc < OCB; ++oc) {
        float bv = gb[oc0 + oc];
#pragma unroll
        for (int k = 0; k < 4; ++k) acc[oc][k] = bv;
    }

    const int rr = lane >> 3;            // row within wave strip (0..7)
    const int tk = lane & 7;             // col group -> cols 4tk..4tk+3
    // taps for output cols tx0+4tk+k: halo words 4tk+k .. 4tk+k+2
    const float* t0 = myt + rr * HSTR + 4 * tk;

    for (int ic = 0; ic < NC; ++ic) {
        // issue global loads for ic+1 early
        float nxt[NSLOT];
        if (ic + 1 < NC) {
            const float* src = cb + (ic + 1) * HW;
#pragma unroll
            for (int s = 0; s < NSLOT; ++s) nxt[s] = src[off[s]] * msk[s];
        }

        // stencil: 3 rows x 6 b32 reads (words 4tk..4tk+5)
        float v[3][6];
#pragma unroll
        for (int r = 0; r < 3; ++r)
#pragma unroll
            for (int j = 0; j < 6; ++j)
                v[r][j] = t0[r * HSTR + j];

        const float* wb = gw + (oc0 * NC + ic) * 9;
#pragma unroll
        for (int oc = 0; oc < OCB; ++oc) {
            const float* w9 = wb + oc * (NC * 9);
#pragma unroll
            for (int r = 0; r < 3; ++r) {
                float wa = w9[r * 3], wbv = w9[r * 3 + 1], wc = w9[r * 3 + 2];
#pragma unroll
                for (int k = 0; k < 4; ++k)
                    acc[oc][k] += v[r][k] * wa + v[r][k + 1] * wbv + v[r][k + 2] * wc;
            }
        }

        // write ic+1 (vmcnt waits land here, behind the FMA block)
        if (ic + 1 < NC) {
#pragma unroll
            for (int s = 0; s < NSLOT; ++s)
                if (stv[s]) myt[lane + s * 64] = nxt[s];
        }
    }

    const int p = b * HW + (ty0 + wrow0 + rr) * NW + (tx0 + 4 * tk);
#pragma unroll
    for (int oc = 0; oc < OCB; ++oc) {
        float4 o;
        o.x = acc[oc][0]; o.y = acc[oc][1]; o.z = acc[oc][2]; o.w = acc[oc][3];
        *(float4*)(wts + (size_t)(oc0 + oc) * NP + p) = o;
    }
}

// ---------------------------------------------------------------------------
// kan helpers
// ---------------------------------------------------------------------------
__device__ __forceinline__ float spline_part(float xv, const float* cb, int d)
{
    // cardinal cubic B-spline on uniform knots; cb = scoef + lane,
    // coef gather at LDS stride 64 words (bank = lane%32, 2-way = free)
    float t = (xv + 2.2f) * 2.5f;
    float fi = floorf(t);
    int i = (int)fi;
    float u = t - fi;
    float u2 = u * u, u3 = u2 * u;
    float um = 1.f - u;
    float w0 = um * um * um * (1.f / 6.f);
    float w3 = u3 * (1.f / 6.f);
    float w1 = (3.f * u3 - 6.f * u2 + 4.f) * (1.f / 6.f);
    float w2 = 1.f - w0 - w1 - w3;          // partition of unity
    int j0 = i - 3;
    float sd = 0.f;
#pragma unroll
    for (int k = 0; k < 4; ++k) {
        int j = j0 + k;
        bool valid = (j >= 0) && (j <= 7);
        int jc = valid ? j : 0;
        float wk = (k == 0) ? w0 : (k == 1) ? w1 : (k == 2) ? w2 : w3;
        float cf = cb[(d * NBASIS + jc) * KPPB];
        sd += (valid ? wk : 0.f) * cf;
    }
    return sd;
}

__device__ __forceinline__ float silu(float xv)
{
    return xv / (1.f + __expf(-xv));
}

// ---------------------------------------------------------------------------
// Kernel 3 (v7, reverted from v8's b128 staging): block = 64 pixels, 4 waves.
// All 70 wts rows staged to LDS [k][64] via b32 (2/bank = free). Wave wv
// processes 8 channels as 4 pairs (two independent spline chains per d).
// Wave 3 covers channels 23..30 (ch 23 duplicated, identical -> benign).
// grid = 1152 blocks.
// ---------------------------------------------------------------------------
__global__ __launch_bounds__(256, 3) void kan_kernel(
    const float* __restrict__ x, const float* __restrict__ wts,
    float* __restrict__ out)
{
    __shared__ float scoef[KP * KPPB];   // 70*64*4 = 17920 B
    const int tid = threadIdx.x;
    const int p0  = blockIdx.x * KPPB;

    // stage all 70 wts rows: f = k*64 + pix, fully coalesced b32
    for (int f = tid; f < KP * KPPB; f += 256)
        scoef[f] = wts[(size_t)(f >> 6) * NP + p0 + (f & 63)];

    __syncthreads();

    const int lane = tid & 63;
    const int wv   = tid >> 6;
    const int p    = p0 + lane;
    const int b    = p / HW;              // uniform (HW % 64 == 0)
    const int hw   = p - b * HW;

    const float* cb64 = scoef + lane;

    float uw[ND], rw[ND];
#pragma unroll
    for (int d = 0; d < ND; ++d) uw[d] = cb64[(CLEN + d) * KPPB];
#pragma unroll
    for (int d = 0; d < ND; ++d) rw[d] = cb64[(CLEN + ND + d) * KPPB];

    const float* xb = x + (size_t)(b * NC) * (ND * HW) + hw;
    float* ob = out + (b * NC) * HW + hw;

    const int c_begin = (wv == 3) ? 23 : wv * 8;   // 8 channels per wave

#pragma unroll
    for (int i = 0; i < 4; ++i) {
        const int c0 = c_begin + 2 * i;
        const int c1 = c0 + 1;
        const float* x0 = xb + (size_t)c0 * ND * HW;
        const float* x1 = xb + (size_t)c1 * ND * HW;
        float s0 = 0.f, s1 = 0.f;
#pragma unroll
        for (int d = 0; d < ND; ++d) {
            float xv0 = x0[d * HW];
            float xv1 = x1[d * HW];
            s0 += uw[d] * spline_part(xv0, cb64, d) + rw[d] * silu(xv0);
            s1 += uw[d] * spline_part(xv1, cb64, d) + rw[d] * silu(xv1);
        }
        ob[c0 * HW] = s0;
        ob[c1 * HW] = s1;
    }
}

// ---------------------------------------------------------------------------
extern "C" void kernel_launch(void* const* d_in, const int* in_sizes, int n_in,
                              void* d_out, int out_size, void* d_ws, size_t ws_size,
                              hipStream_t stream)
{
    const float* x  = (const float*)d_in[0];   // (2,31,7,192,192)
    const float* gw = (const float*)d_in[1];   // (70,31,3,3)
    const float* gb = (const float*)d_in[2];   // (70,)
    float* out = (float*)d_out;                // (2,31,192,192)

    float* ctx = (float*)d_ws;                       // 9.1 MB
    float* wts = ctx + (size_t)NBATCH * NC * HW;     // 20.6 MB

    int n4 = NBATCH * NC * (HW / 4);
    ctx_mean_kernel<<<dim3((n4 + 255) / 256), 256, 0, stream>>>(
        (const float4*)x, (float4*)ctx);
    conv_kernel<<<dim3(NW / CTS, (NH / CTS) * NBATCH, KP / OCB), 256, 0, stream>>>(ctx, gw, gb, wts);
    kan_kernel<<<dim3(NP / KPPB), 256, 0, stream>>>(x, wts, out);
}